// Round 5
// baseline (769.277 us; speedup 1.0000x reference)
//
#include <hip/hip_runtime.h>
#include <hip/hip_bf16.h>

// Problem constants
#define BB 32    // batch
#define TT 128   // T_E == T_D
#define HH 256   // hidden
#define G4 4     // blocks per batch for LSTM
#define UPB 64   // units per LSTM slice (256/4)

#define AGENT __HIP_MEMORY_SCOPE_AGENT
#define AL(p) __hip_atomic_load((p), __ATOMIC_RELAXED, AGENT)
#define AS(p, v) __hip_atomic_store((p), (v), __ATOMIC_RELAXED, AGENT)

__device__ __forceinline__ float rcp_f(float x) { return __builtin_amdgcn_rcpf(x); }
__device__ __forceinline__ float sigmoid_f(float x) {
    return rcp_f(1.f + __expf(-x));  // ~1e-7 rel err vs 7e-3 threshold
}
__device__ __forceinline__ float tanh_f(float x) {
    float e = __expf(2.f * x);
    return 1.f - 2.f * rcp_f(e + 1.f);
}

// ---------------------------------------------------------------------------
// LSTM + fused projections — R20: k-partitioned partial-sum exchange.
// grid = 128 (blk = g*32+b); block = 512 = 8 waves.
//
// DECOMPOSITION FLIP vs R12..R19 (which partitioned by unit rows):
//   block g holds Whh[all 1024 rows][k-slice g*64..+64].
//   dot(t) consumes ONLY h_own[64] (local!) -> partial gate sums for all
//   1024 rows -> publish the 768 foreign-owned partials (tagged packets),
//   poll 3x256 partials from partners, sum 4-way at the owner, act on own
//   64 units, h stays local. The serial cycle becomes
//     act -> dot(own-h, ~600cy) -> publish -> RTT -> detect/sum -> act
//   i.e. the big dot moved OFF the post-RTT segment (old: RTT -> barB ->
//   full 256-wide dot ~1100-1280cy -> act). h is published only for the
//   off-chain e2/d2 projections, polled with a 2-step lag (never waits).
//   hsave boundary exchange deleted (dot(TT) needs only own h_saved).
// Measured ledger:
//   R12 545 | R13 scratch 1449 | R14 rotated 645 | R15 484 (best, row-split)
//   R16 lgkm-barrier NULL | R17 gate-colocate 706 | R18 pk_fma 589 (no f32
//   pk gain on gfx950) | R19 XCD-coloring NULL (RTT placement-invariant)
// Pre-commit: >=480us => RTT/detect floor; restore R15 and declare.
// ---------------------------------------------------------------------------
__global__ __launch_bounds__(512, 2) void lstm_kernel(
    const float* __restrict__ seq,     // [B][128]
    const int* __restrict__ seq_m,     // [B]
    const float* __restrict__ target,  // [B][128]
    const float* __restrict__ Wih_e,   // [1024]
    const float* __restrict__ Whh_e,   // [1024][256]
    const float* __restrict__ bih_e, const float* __restrict__ bhh_e,
    const float* __restrict__ Wih_d, const float* __restrict__ Whh_d,
    const float* __restrict__ bih_d, const float* __restrict__ bhh_d,
    const float* __restrict__ We, const float* __restrict__ be,
    const float* __restrict__ Wd, const float* __restrict__ bd,
    float* __restrict__ e2,  // [B][128][256]
    float* __restrict__ d2,  // [B][128][256]
    unsigned long long* __restrict__ mbox_p,  // [2][B][3][1024] tagged partials
    unsigned long long* __restrict__ mbox_h)  // [2][B][256] tagged h (for proj)
{
    const int blk = blockIdx.x;
    const int b = blk & 31;   // batch
    const int g = blk >> 5;   // k-slice / unit-owner 0..3
    const int tid = threadIdx.x;
    const int last = seq_m[b] - 1;

    // dot rows: thread owns rows r0 = 2*tid and r0+1 (row = gate*256 + unit)
    const int r0 = tid << 1;
    const int gate_t = r0 >> 8;       // 0..3 (same for both rows)
    const int unit0 = r0 & 255;       // even; unit1 = unit0+1, same owner
    const int owner = unit0 >> 6;     // block owning these units
    const int uo = (gate_t << 6) | (unit0 & 63);     // own_p index (even)
    const int slot_s = (g - owner + 3) & 3;          // sender slot at owner

    // poller role (tid 64..255): slot 0..2, lane = unit offset
    const int q = tid - 64;
    const int pslot = q >> 6;
    const int plane = q & 63;

    // proj role (tid >= 256): col g*64+(s>>2); k-quarter s&3
    const int s = tid - 256;
    const int pu = s >> 2;
    const int kq = s & 3;
    const int pcol = g * UPB + pu;

    __shared__ float h_lds[UPB];      // own h(t-1), single-buffered (barriers)
    __shared__ float own_p[256];      // own-rows partials [gate][64]
    __shared__ float psum[3 * 256];   // polled partials [slot][gate][64]
    __shared__ float x_lds[2 * TT];
    __shared__ float h_full[2][HH];   // lagged full h for proj (parity bufs)

    for (int i = tid; i < TT; i += 512) {
        x_lds[i] = seq[b * TT + i];
        x_lds[TT + i] = target[b * TT + i];
    }

    // weights: rows r0, r0+1, k-slice [g*64, g*64+64) — 32 float4 total
    float4 w0[16], w1[16];
    auto loadw = [&](const float* Whh) {
        const float4* a = (const float4*)(Whh + r0 * HH + g * UPB);
        const float4* c2 = (const float4*)(Whh + (r0 + 1) * HH + g * UPB);
#pragma unroll
        for (int i = 0; i < 16; ++i) { w0[i] = a[i]; w1[i] = c2[i]; }
    };
    loadw(Whh_e);

    // wave0 activation constants (bias + Wih for own 64 units x 4 gates)
    float bact[4], wact[4];
    auto loadact = [&](const float* Wih, const float* bih, const float* bhh) {
        if (tid < 64) {
#pragma unroll
            for (int k = 0; k < 4; ++k) {
                const int rg = k * HH + g * UPB + tid;
                bact[k] = bih[rg] + bhh[rg];
                wact[k] = Wih[rg];
            }
        }
    };
    loadact(Wih_e, bih_e, bhh_e);

    float4 pw[16];
    float pb = 0.f;
    auto loadp = [&](const float* W, const float* bias) {
        const float4* src = (const float4*)(W + pcol * HH + kq * 64);
#pragma unroll
        for (int i = 0; i < 16; ++i) pw[i] = src[i];
        pb = bias[pcol];
    };
    if (tid >= 256) loadp(We, be);

    // plain proj dot: static offsets (R12-proven), src = lagged h_full buffer
    auto projdot = [&](const float* hsrc) -> float {
        const float4* hp = (const float4*)(hsrc + kq * 64);
        float pa = 0.f;
#pragma unroll
        for (int i = 0; i < 16; ++i) {
            float4 hv = hp[i];
            pa = fmaf(pw[i].x, hv.x, pa);
            pa = fmaf(pw[i].y, hv.y, pa);
            pa = fmaf(pw[i].z, hv.z, pa);
            pa = fmaf(pw[i].w, hv.w, pa);
        }
        pa += __shfl_xor(pa, 1);
        pa += __shfl_xor(pa, 2);  // 4 k-quarters combined
        return pa + pb;
    };

    if (tid < 64) h_lds[tid] = 0.f;  // h(-1) = 0
    __syncthreads();

    float c = 0.f, c_saved = 0.f, h_saved = 0.f;

    for (int t = 0; t < 2 * TT; ++t) {
        const int phase = t >> 7;  // 0 = encoder, 1 = decoder
        const int tt = t & 127;
        const int par = t & 1;
        const unsigned tag = (unsigned)(t + 1);

        // ---- dot: partials for rows r0, r0+1 over OWN 64-wide h chunk ----
        float a0 = 0.f, a1 = 0.f;
        const float4* hp = (const float4*)h_lds;  // broadcast reads (free)
#pragma unroll
        for (int i = 0; i < 16; ++i) {
            float4 hv = hp[i];
            a0 = fmaf(w0[i].x, hv.x, a0);
            a0 = fmaf(w0[i].y, hv.y, a0);
            a0 = fmaf(w0[i].z, hv.z, a0);
            a0 = fmaf(w0[i].w, hv.w, a0);
            a1 = fmaf(w1[i].x, hv.x, a1);
            a1 = fmaf(w1[i].y, hv.y, a1);
            a1 = fmaf(w1[i].z, hv.z, a1);
            a1 = fmaf(w1[i].w, hv.w, a1);
        }
        // ---- publish partials (foreign) / stash (own) ----
        if (owner == g) {
            *(float2*)&own_p[uo] = make_float2(a0, a1);
        } else {
            unsigned long long* dst =
                mbox_p + ((size_t)(par * BB + b) * 3 + slot_s) * 1024 + r0;
            AS(dst, ((unsigned long long)tag << 32) | __float_as_uint(a0));
            AS(dst + 1, ((unsigned long long)tag << 32) | __float_as_uint(a1));
        }

        // ---- pollers (waves 1-3): 4 gate-partials each from one partner ----
        if (tid >= 64 && tid < 256) {
            unsigned long long* base =
                mbox_p + ((size_t)(par * BB + b) * 3 + pslot) * 1024 + g * UPB + plane;
            unsigned long long* p0 = base;        // gate i row
            unsigned long long* p1 = base + 256;  // gate f
            unsigned long long* p2 = base + 512;  // gate g
            unsigned long long* p3 = base + 768;  // gate o
            unsigned long long c0 = AL(p0), c1 = AL(p1), c2v = AL(p2), c3 = AL(p3);
            for (;;) {
                const bool e0 = (unsigned)(c0 >> 32) == tag;
                const bool e1 = (unsigned)(c1 >> 32) == tag;
                const bool e2v = (unsigned)(c2v >> 32) == tag;
                const bool e3 = (unsigned)(c3 >> 32) == tag;
                if (e0 & e1 & e2v & e3) break;
                if (!e0) c0 = AL(p0);
                if (!e1) c1 = AL(p1);
                if (!e2v) c2v = AL(p2);
                if (!e3) c3 = AL(p3);
            }
            psum[pslot * 256 + 0 + plane] = __uint_as_float((unsigned)c0);
            psum[pslot * 256 + 64 + plane] = __uint_as_float((unsigned)c1);
            psum[pslot * 256 + 128 + plane] = __uint_as_float((unsigned)c2v);
            psum[pslot * 256 + 192 + plane] = __uint_as_float((unsigned)c3);
        }

        // ---- proj (waves 4-7): assemble lagged h, project row t-2 ----
        if (tid >= 256) {
            if (t >= 1) {  // poll h(t-1), tag t — published last step, no wait
                unsigned long long* hsrc =
                    mbox_h + (size_t)(((t - 1) & 1) * BB + b) * HH + s;
                unsigned long long r = AL(hsrc);
                while ((unsigned)(r >> 32) != (unsigned)t) r = AL(hsrc);
                h_full[(t - 1) & 1][s] = __uint_as_float((unsigned)r);
            }
            if (t >= 2) {  // project h(t-2) from the buffer assembled last step
                const int row = t - 2;
                float pv = projdot(h_full[par]);  // (t-2)&1 == par
                if (kq == 0) {
                    if (row < TT)
                        e2[(b * TT + row) * HH + pcol] = pv;
                    else
                        d2[(b * TT + row - TT) * HH + pcol] = pv;
                }
                if (t == TT + 1) loadp(Wd, bd);  // rows >= TT use Wd
            }
        }

        __syncthreads();  // (A) own_p/psum visible to wave0

        // ---- wave0: gather 4-way sums + act + publish h ----
        if (tid < 64) {
            const float x = x_lds[t];
            float gi = own_p[0 * 64 + tid] + psum[0 * 256 + 0 * 64 + tid] +
                       psum[1 * 256 + 0 * 64 + tid] + psum[2 * 256 + 0 * 64 + tid] +
                       bact[0] + x * wact[0];
            float gf = own_p[1 * 64 + tid] + psum[0 * 256 + 1 * 64 + tid] +
                       psum[1 * 256 + 1 * 64 + tid] + psum[2 * 256 + 1 * 64 + tid] +
                       bact[1] + x * wact[1];
            float gg = own_p[2 * 64 + tid] + psum[0 * 256 + 2 * 64 + tid] +
                       psum[1 * 256 + 2 * 64 + tid] + psum[2 * 256 + 2 * 64 + tid] +
                       bact[2] + x * wact[2];
            float go = own_p[3 * 64 + tid] + psum[0 * 256 + 3 * 64 + tid] +
                       psum[1 * 256 + 3 * 64 + tid] + psum[2 * 256 + 3 * 64 + tid] +
                       bact[3] + x * wact[3];
            float si = sigmoid_f(gi);
            float sf = sigmoid_f(gf);
            float tg = tanh_f(gg);
            float so = sigmoid_f(go);
            c = sf * c + si * tg;
            float h = so * tanh_f(c);
            const int ug = g * UPB + tid;
            AS(&mbox_h[(size_t)(par * BB + b) * HH + ug],
               ((unsigned long long)tag << 32) | __float_as_uint(h));
            if (phase == 0 && tt == last) {
                c_saved = c;
                h_saved = h;
            }
            h_lds[tid] = (t == TT - 1) ? h_saved : h;  // dot(TT) uses e_hs
        }

        __syncthreads();  // (B) h_lds ready for next dot; psum consumed

        if (t == TT - 1) {  // encoder -> decoder transition (all local now)
            loadw(Whh_d);
            loadact(Wih_d, bih_d, bhh_d);
            c = c_saved;
        }
    }

    // ---- post-loop: d2 rows TT-2 (h(2TT-2), already assembled in
    // h_full[0]) and TT-1 (poll h(2TT-1), tag 2TT, parity 1) ----
    if (tid >= 256) {
        float pv = projdot(h_full[0]);
        if (kq == 0) d2[(b * TT + TT - 2) * HH + pcol] = pv;
        unsigned long long* hsrc = mbox_h + (size_t)(1 * BB + b) * HH + s;
        unsigned long long r = AL(hsrc);
        while ((unsigned)(r >> 32) != (unsigned)(2 * TT)) r = AL(hsrc);
        h_full[1][s] = __uint_as_float((unsigned)r);
    }
    __syncthreads();
    if (tid >= 256) {
        float pv = projdot(h_full[1]);
        if (kq == 0) d2[(b * TT + TT - 1) * HH + pcol] = pv;
    }
}

// ---------------------------------------------------------------------------
// Attention scores: p = tanh(e2_j + d2_i) . v  for a 32x32 (i,j) tile.
// grid = 512 = b(32) x it(4) x jt(4); block = 256; 4x i-register-blocked.
// ---------------------------------------------------------------------------
#define EPAD 260  // float4-aligned LDS row stride
__global__ __launch_bounds__(256) void attn_p_kernel(
    const float* __restrict__ e2, const float* __restrict__ d2,
    const float* __restrict__ vv, float* __restrict__ p_ws) {
    __shared__ float e2c[32][EPAD];
    __shared__ float d2t[32][EPAD];
    __shared__ float v_lds[HH];

    const int blk = blockIdx.x;
    const int b = blk >> 4;
    const int i0 = ((blk >> 2) & 3) * 32;
    const int j0 = (blk & 3) * 32;
    const int tid = threadIdx.x;
    const int jl = tid & 31, ig = tid >> 5;

    if (tid < 64) *(float4*)&v_lds[tid * 4] = ((const float4*)vv)[tid];
    for (int idx = tid; idx < 32 * 64; idx += 256) {
        int r = idx >> 6, q = idx & 63;
        *(float4*)&d2t[r][q * 4] = ((const float4*)(d2 + (b * TT + i0 + r) * HH))[q];
        *(float4*)&e2c[r][q * 4] = ((const float4*)(e2 + (b * TT + j0 + r) * HH))[q];
    }
    __syncthreads();

    float a0 = 0.f, a1 = 0.f, a2 = 0.f, a3 = 0.f;
    for (int h = 0; h < HH; h += 4) {
        float4 ev = *(const float4*)&e2c[jl][h];
        float4 vx = *(const float4*)&v_lds[h];
        float4 d0 = *(const float4*)&d2t[ig * 4 + 0][h];
        float4 d1 = *(const float4*)&d2t[ig * 4 + 1][h];
        float4 d2v = *(const float4*)&d2t[ig * 4 + 2][h];
        float4 d3 = *(const float4*)&d2t[ig * 4 + 3][h];
        a0 = fmaf(tanh_f(ev.x + d0.x), vx.x, a0);
        a0 = fmaf(tanh_f(ev.y + d0.y), vx.y, a0);
        a0 = fmaf(tanh_f(ev.z + d0.z), vx.z, a0);
        a0 = fmaf(tanh_f(ev.w + d0.w), vx.w, a0);
        a1 = fmaf(tanh_f(ev.x + d1.x), vx.x, a1);
        a1 = fmaf(tanh_f(ev.y + d1.y), vx.y, a1);
        a1 = fmaf(tanh_f(ev.z + d1.z), vx.z, a1);
        a1 = fmaf(tanh_f(ev.w + d1.w), vx.w, a1);
        a2 = fmaf(tanh_f(ev.x + d2v.x), vx.x, a2);
        a2 = fmaf(tanh_f(ev.y + d2v.y), vx.y, a2);
        a2 = fmaf(tanh_f(ev.z + d2v.z), vx.z, a2);
        a2 = fmaf(tanh_f(ev.w + d2v.w), vx.w, a2);
        a3 = fmaf(tanh_f(ev.x + d3.x), vx.x, a3);
        a3 = fmaf(tanh_f(ev.y + d3.y), vx.y, a3);
        a3 = fmaf(tanh_f(ev.z + d3.z), vx.z, a3);
        a3 = fmaf(tanh_f(ev.w + d3.w), vx.w, a3);
    }
    float* pr = p_ws + (b * TT + i0 + ig * 4) * TT + j0 + jl;
    pr[0 * TT] = a0;
    pr[1 * TT] = a1;
    pr[2 * TT] = a2;
    pr[3 * TT] = a3;
}

// ---------------------------------------------------------------------------
// Softmax over j with mask (memory-bound finisher).
// grid = 256 = b(32) x 8 row-tiles (16 rows); block = 256 (16 rows x 16 lanes).
// ---------------------------------------------------------------------------
__global__ __launch_bounds__(256) void attn_sm_kernel(
    const float* __restrict__ p_ws, const float* __restrict__ seq,
    float* __restrict__ out) {
    const int blk = blockIdx.x;
    const int b = blk >> 3;
    const int r0 = (blk & 7) * 16;
    const int tid = threadIdx.x;
    const int r = tid >> 4, l16 = tid & 15;
    const int row = (b * TT + r0 + r) * TT;

    float xr[8];
    float m = -1e30f;
#pragma unroll
    for (int k = 0; k < 8; ++k) {
        const int j = l16 + 16 * k;
        float x = p_ws[row + j];
        float sv = (j == 0) ? 0.1f : seq[b * TT + j];
        if (sv == 0.f) x -= 1000.f;
        xr[k] = x;
        m = fmaxf(m, x);
    }
#pragma unroll
    for (int o = 8; o >= 1; o >>= 1) m = fmaxf(m, __shfl_xor(m, o));
    float s = 0.f;
#pragma unroll
    for (int k = 0; k < 8; ++k) {
        xr[k] = __expf(xr[k] - m);
        s += xr[k];
    }
#pragma unroll
    for (int o = 8; o >= 1; o >>= 1) s += __shfl_xor(s, o);
    float inv = rcp_f(s);
#pragma unroll
    for (int k = 0; k < 8; ++k) out[row + l16 + 16 * k] = xr[k] * inv;
}

// ---------------------------------------------------------------------------
extern "C" void kernel_launch(void* const* d_in, const int* in_sizes, int n_in,
                              void* d_out, int out_size, void* d_ws, size_t ws_size,
                              hipStream_t stream) {
    const float* seq = (const float*)d_in[0];
    const int* seq_m = (const int*)d_in[1];
    const float* target = (const float*)d_in[2];
    const float* Wih_e = (const float*)d_in[3];
    const float* Whh_e = (const float*)d_in[4];
    const float* bih_e = (const float*)d_in[5];
    const float* bhh_e = (const float*)d_in[6];
    const float* Wih_d = (const float*)d_in[7];
    const float* Whh_d = (const float*)d_in[8];
    const float* bih_d = (const float*)d_in[9];
    const float* bhh_d = (const float*)d_in[10];
    const float* We = (const float*)d_in[11];
    const float* be = (const float*)d_in[12];
    const float* Wd = (const float*)d_in[13];
    const float* bd = (const float*)d_in[14];
    const float* vv = (const float*)d_in[15];

    float* ws = (float*)d_ws;
    const size_t SZ_ED = (size_t)BB * TT * HH;  // 1,048,576 floats
    float* e2 = ws;
    float* d2 = e2 + SZ_ED;
    float* p_ws = d2 + SZ_ED;  // [B][128][128]
    unsigned long long* mbox_p =
        (unsigned long long*)(p_ws + (size_t)BB * TT * TT);  // [2][B][3][1024]
    unsigned long long* mbox_h = mbox_p + (size_t)2 * BB * 3 * 1024;  // [2][B][256]

    const size_t n_pkts = (size_t)2 * BB * 3 * 1024 + (size_t)2 * BB * HH;
    const size_t needed = (2 * SZ_ED + (size_t)BB * TT * TT) * sizeof(float) +
                          n_pkts * sizeof(unsigned long long);
    if (ws_size < needed) return;

    hipMemsetAsync(mbox_p, 0, n_pkts * sizeof(unsigned long long), stream);
    lstm_kernel<<<BB * G4, 512, 0, stream>>>(seq, seq_m, target, Wih_e, Whh_e, bih_e,
                                             bhh_e, Wih_d, Whh_d, bih_d, bhh_d, We,
                                             be, Wd, bd, e2, d2, mbox_p, mbox_h);
    attn_p_kernel<<<512, 256, 0, stream>>>(e2, d2, vv, p_ws);
    attn_sm_kernel<<<256, 256, 0, stream>>>(p_ws, seq, (float*)d_out);
}